// Round 13
// baseline (86.754 us; speedup 1.0000x reference)
//
#include <hip/hip_runtime.h>
#include <hip/hip_bf16.h>
#include <stdint.h>

// Batched NT-GEMM: out[b,i,j] = sum_d m1[b,i,d] * m2[b,j,d]
// B=16, M=N=2048, K=256, fp32 in/out; f16 MFMA compute.
//
// Round 13 = R7 base (75.8us) + ONE change: SWAPPED MFMA OPERANDS so the
// accumulator is row-contiguous per lane -> dwordx4 epilogue stores.
//   mfma(bf[n], af[m], acc): X-index ((l>>4)*4+reg) walks B's 16 rows
//   (= C columns), Y-index (l&15) walks A's 16 rows (= C rows). Lane's
//   4 regs = 4 consecutive C columns of one row -> one nt dwordx4 store
//   per fragment: 64 scalar stores/thread -> 16 vector stores/thread.
//   (R6/R9/R12 proved block-level store restructuring costs more than it
//   hides; this attacks the store ISSUE pattern instead, at zero cost.)

typedef _Float16 f16x8 __attribute__((ext_vector_type(8)));
typedef _Float16 f16x4 __attribute__((ext_vector_type(4)));
typedef _Float16 f16x2 __attribute__((ext_vector_type(2)));
typedef float f32x4 __attribute__((ext_vector_type(4)));

#define NB 16
#define DM 2048
#define DN 2048
#define DK 256
#define BM 128
#define BN 128
#define BK 32
#define BKP 36                          // padded LDS row stride (elements)
#define NT (DK / BK)                    // 8 K-steps
#define NWG (NB * (DM/BM) * (DN/BN))    // 4096 blocks

// lgkm-only barrier: LDS writes published, VMEM ops stay outstanding.
#define LDS_BARRIER() do {                                   \
    asm volatile("s_waitcnt lgkmcnt(0)" ::: "memory");       \
    __builtin_amdgcn_s_barrier();                            \
    asm volatile("" ::: "memory");                           \
} while (0)

__global__ __launch_bounds__(256, 2) void fused_gemm(const float* __restrict__ A,
                                                     const float* __restrict__ B,
                                                     float* __restrict__ C) {
    __shared__ _Float16 As[2][BM * BKP];   // 9216 B per buffer
    __shared__ _Float16 Bs[2][BN * BKP];

    const int t = threadIdx.x;

    // XCD swizzle (NWG % 8 == 0 -> bijective); bx fastest within a chunk.
    const int bid = blockIdx.x;
    const int swz = (bid & 7) * (NWG / 8) + (bid >> 3);
    const int b    = swz >> 8;          // 256 blocks per batch
    const int rem  = swz & 255;
    const int brow = (rem >> 4) << 7;   // * BM
    const int bcol = (rem & 15) << 7;   // * BN

    const float* At = A + (size_t)b * DM * DK + (size_t)brow * DK;
    const float* Bt = B + (size_t)b * DN * DK + (size_t)bcol * DK;

    const int w    = t >> 6;
    const int l    = t & 63;
    const int wr   = (w >> 1) * 64;     // wave row offset in tile
    const int wc   = (w & 1) * 64;      // wave col offset in tile
    const int lrow = l & 15;
    const int lko  = (l >> 4) * 8;      // k-offset of lane's 8 f16 elements

    f32x4 acc[4][4] = {};

    // Staging geometry: tile = 128 rows x 32 k fp32 = 1024 float4 chunks;
    // thread t owns chunks c = t + i*256 -> row r = c>>3, quad q = c&7.
    auto issue = [&](int kt, float4 (&va)[4], float4 (&vb)[4]) {
#pragma unroll
        for (int i = 0; i < 4; ++i) {
            const int c = t + i * 256;
            const int r = c >> 3, q = c & 7;
            va[i] = *reinterpret_cast<const float4*>(At + (size_t)r * DK + kt * BK + q * 4);
            vb[i] = *reinterpret_cast<const float4*>(Bt + (size_t)r * DK + kt * BK + q * 4);
        }
    };
    auto cvt4 = [](const float4& v) -> f16x4 {
        f16x2 lo = __builtin_bit_cast(f16x2, __builtin_amdgcn_cvt_pkrtz(v.x, v.y));
        f16x2 hi = __builtin_bit_cast(f16x2, __builtin_amdgcn_cvt_pkrtz(v.z, v.w));
        return f16x4{ lo[0], lo[1], hi[0], hi[1] };
    };
    auto wlds = [&](int buf, const float4 (&va)[4], const float4 (&vb)[4]) {
#pragma unroll
        for (int i = 0; i < 4; ++i) {
            const int c = t + i * 256;
            const int r = c >> 3, q = c & 7;
            *reinterpret_cast<f16x4*>(&As[buf][r * BKP + q * 4]) = cvt4(va[i]);
            *reinterpret_cast<f16x4*>(&Bs[buf][r * BKP + q * 4]) = cvt4(vb[i]);
        }
    };
    auto compute = [&](int buf) {
        f16x8 af[4], bf[4];
#pragma unroll
        for (int m = 0; m < 4; ++m)
            af[m] = *reinterpret_cast<const f16x8*>(&As[buf][(wr + m * 16 + lrow) * BKP + lko]);
#pragma unroll
        for (int n = 0; n < 4; ++n)
            bf[n] = *reinterpret_cast<const f16x8*>(&Bs[buf][(wc + n * 16 + lrow) * BKP + lko]);
        // SWAPPED operands: X=bf[n] -> X-index walks C columns, Y=af[m] ->
        // Y-index walks C rows. Lane's 4 regs = 4 consecutive C columns.
#pragma unroll
        for (int m = 0; m < 4; ++m)
#pragma unroll
            for (int n = 0; n < 4; ++n)
                acc[m][n] = __builtin_amdgcn_mfma_f32_16x16x32_f16(bf[n], af[m], acc[m][n], 0, 0, 0);
    };

    // Two named in-flight register sets (static indexing only - rule #20).
    float4 vaX[4], vbX[4], vaY[4], vbY[4];

    // Prologue: tiles 0 (X) and 1 (Y) in flight; write tile 0 -> buf0.
    issue(0, vaX, vbX);
    issue(1, vaY, vbY);
    wlds(0, vaX, vbX);        // counted wait: Y's loads stay outstanding
    LDS_BARRIER();

    // Steady state, manually unrolled x2 (roles X/Y alternate; buf = kt&1).
#pragma unroll
    for (int k2 = 0; k2 < NT; k2 += 2) {
        if (k2 + 2 < NT) issue(k2 + 2, vaX, vbX);
        compute(0);
        wlds(1, vaY, vbY);                 // counted: X stays in flight
        LDS_BARRIER();

        if (k2 + 3 < NT) issue(k2 + 3, vaY, vbY);
        compute(1);
        if (k2 + 2 < NT) {
            wlds(0, vaX, vbX);             // counted: Y stays in flight
        }
        LDS_BARRIER();
    }

    // Epilogue with swapped layout:
    //   lane l, frag (m,n): C row = brow+wr+m*16+(l&15),
    //                       cols  = bcol+wc+n*16+4*(l>>4) + {0..3}  (one f32x4)
    // 16 nt dwordx4 stores/thread (was 64 scalar). 16B-aligned.
    float* Cb = C + (size_t)b * DM * DN;
    const int crow = brow + wr + lrow;
    const int ccol = bcol + wc + ((l >> 4) << 2);
#pragma unroll
    for (int m = 0; m < 4; ++m) {
        float* rowp = Cb + (size_t)(crow + m * 16) * DN + ccol;
#pragma unroll
        for (int n = 0; n < 4; ++n)
            __builtin_nontemporal_store(acc[m][n], reinterpret_cast<f32x4*>(rowp + n * 16));
    }
}

extern "C" void kernel_launch(void* const* d_in, const int* in_sizes, int n_in,
                              void* d_out, int out_size, void* d_ws, size_t ws_size,
                              hipStream_t stream) {
    const float* m1 = (const float*)d_in[0];
    const float* m2 = (const float*)d_in[1];
    float* out = (float*)d_out;
    (void)d_ws; (void)ws_size;

    fused_gemm<<<NWG, 256, 0, stream>>>(m1, m2, out);
}